// Round 7
// baseline (85.550 us; speedup 1.0000x reference)
//
#include <hip/hip_runtime.h>

// Shapes fixed by reference setup_inputs(): (B=16, NI=11, T=65536), LST=64.
#define B_   16
#define NI   11
#define T_   65536
#define LST  64
#define NBLK (T_ / LST)     // 1024
#define ROWP 68             // LDS row stride (floats): 272B, 16B-aligned

#define DPP_XOR1 0xB1       // quad_perm(1,0,3,2)  == xor lane^1
#define DPP_XOR2 0x4E       // quad_perm(2,3,0,1)  == xor lane^2

// DIAGNOSTIC ROUND: recompute both tau solves REPS times (asm-opaque inputs
// force real re-execution; results identical each pass -> output exact).
// Memory traffic unchanged; compute x5. T_compute = (dur - 28.5)/4.
#define REPS 5

__device__ __forceinline__ float frcp(float x) { return __builtin_amdgcn_rcpf(x); }

template<int CTRL>
__device__ __forceinline__ float dppf(float x) {
    return __int_as_float(__builtin_amdgcn_update_dpp(
        0, __float_as_int(x), CTRL, 0xF, 0xF, true));
}
template<int CTRL>
__device__ __forceinline__ int dppi(int x) {
    return __builtin_amdgcn_update_dpp(0, x, CTRL, 0xF, 0xF, true);
}

__global__ __launch_bounds__(256) void fused_sparsemax_diag(
        const float* __restrict__ in, float* __restrict__ out) {
    __shared__ float ldsz[4][NI * ROWP];   // z tile, row-major [inst][t]
    __shared__ float ldsti[4][64];         // tau_inst[t] transpose buffer

    const int lane = threadIdx.x & 63;
    const int wid  = threadIdx.x >> 6;
    const int tile = blockIdx.x * 4 + wid;          // 16384 tiles
    const int b    = tile >> 10;
    const int jb   = tile & (NBLK - 1);

    const float* px = in + (size_t)b * NI * T_ + (size_t)jb * LST + (size_t)lane;

    // ---- load: 11 coalesced 4B loads (one per instrument row) ----
    float z[NI];
#pragma unroll
    for (int i = 0; i < NI; ++i) z[i] = px[(size_t)i * T_];

    // stage tile to LDS early
#pragma unroll
    for (int i = 0; i < NI; ++i) ldsz[wid][i * ROWP + lane] = z[i];

    // transposed view for the time solve
    const int g   = lane >> 2;
    const int q   = lane & 3;
    const int row = (g < NI) ? g : (g - NI);        // spare groups duplicate

    float y[16];                                    // 4x ds_read_b128
#pragma unroll
    for (int r = 0; r < 16; ++r) y[r] = ldsz[wid][row * ROWP + q * 16 + r];

    float tau_i = 0.0f, tau = 0.0f;

#pragma unroll 1
    for (int rep = 0; rep < REPS; ++rep) {
        // opacity barrier: compiler must assume z/y changed -> full recompute
#pragma unroll
        for (int i = 0; i < NI; ++i) asm volatile("" : "+v"(z[i]));
#pragma unroll
        for (int r = 0; r < 16; ++r) asm volatile("" : "+v"(y[r]));

        // ---- instrument tau: per-lane max-init Michelot over d=11 ----
        float mx = z[0];
#pragma unroll
        for (int i = 1; i < NI; ++i) mx = fmaxf(mx, z[i]);
        tau_i = mx - 1.0f;
        int prevc = 0;
        for (int it = 0; it < NI + 1; ++it) {
            float s = 0.0f;
            int   c = 0;
#pragma unroll
            for (int i = 0; i < NI; ++i) {
                bool a = z[i] > tau_i;
                s += a ? z[i] : 0.0f;
                c += a ? 1 : 0;
            }
            if (!__any(c != prevc)) break;          // support stable -> exact
            prevc = c;
            tau_i = (s - 1.0f) * frcp((float)c);
        }

        // ---- time tau: 4-lane group g owns instrument row g ----
        float m = y[0];
#pragma unroll
        for (int r = 1; r < 16; ++r) m = fmaxf(m, y[r]);
        m = fmaxf(m, dppf<DPP_XOR1>(m));
        m = fmaxf(m, dppf<DPP_XOR2>(m));

        tau = m - 1.0f;
        int prev = 0;
        for (int it = 0; it < LST + 1; ++it) {
            float s = 0.0f;
            int   c = 0;
#pragma unroll
            for (int r = 0; r < 16; ++r) {
                bool a = y[r] > tau;
                s += a ? y[r] : 0.0f;
                c += a ? 1 : 0;
            }
            s += dppf<DPP_XOR1>(s);
            s += dppf<DPP_XOR2>(s);
            c += dppi<DPP_XOR1>(c);
            c += dppi<DPP_XOR2>(c);
            if (!__any(c != prev)) break;           // all groups stable
            prev = c;
            tau = (s - 1.0f) * frcp((float)c);
        }
    }

    ldsti[wid][lane] = tau_i;                       // lane == t within block

    // ---- epilogue in group layout: float4 stores, tau_inst via LDS ----
    if (g < NI) {
        float ti[16];                               // 4x ds_read_b128
#pragma unroll
        for (int r = 0; r < 16; ++r) ti[r] = ldsti[wid][q * 16 + r];

        float* po = out + (size_t)b * NI * T_ + (size_t)g * T_
                        + (size_t)jb * LST + (size_t)q * 16;
        float4* po4 = reinterpret_cast<float4*>(po);
#pragma unroll
        for (int v = 0; v < 4; ++v) {
            float4 o;
            o.x = fmaxf(y[4*v+0] - tau, 0.0f) * fmaxf(y[4*v+0] - ti[4*v+0], 0.0f);
            o.y = fmaxf(y[4*v+1] - tau, 0.0f) * fmaxf(y[4*v+1] - ti[4*v+1], 0.0f);
            o.z = fmaxf(y[4*v+2] - tau, 0.0f) * fmaxf(y[4*v+2] - ti[4*v+2], 0.0f);
            o.w = fmaxf(y[4*v+3] - tau, 0.0f) * fmaxf(y[4*v+3] - ti[4*v+3], 0.0f);
            po4[v] = o;
        }
    }
}

extern "C" void kernel_launch(void* const* d_in, const int* in_sizes, int n_in,
                              void* d_out, int out_size, void* d_ws, size_t ws_size,
                              hipStream_t stream) {
    const float* in = (const float*)d_in[0];
    float* out = (float*)d_out;
    // 16384 wave-tiles, 4 waves per 256-thread block -> 4096 blocks
    hipLaunchKernelGGL(fused_sparsemax_diag, dim3(4096), dim3(256), 0, stream,
                       in, out);
}

// Round 9
// 65.536 us; speedup vs baseline: 1.3054x; 1.3054x over previous
//
#include <hip/hip_runtime.h>

// Shapes fixed by reference setup_inputs(): (B=16, NI=11, T=65536), LST=64.
#define B_   16
#define NI   11
#define T_   65536
#define LST  64
#define NBLK (T_ / LST)     // 1024
#define ROWP 68             // LDS row stride (floats): 272B, 16B-aligned

#define DPP_XOR1 0xB1       // quad_perm(1,0,3,2)  == xor lane^1
#define DPP_XOR2 0x4E       // quad_perm(2,3,0,1)  == xor lane^2

typedef float f32x4 __attribute__((ext_vector_type(4)));  // NT-store-compatible

__device__ __forceinline__ float frcp(float x) { return __builtin_amdgcn_rcpf(x); }

template<int CTRL>
__device__ __forceinline__ float dppf(float x) {
    return __int_as_float(__builtin_amdgcn_update_dpp(
        0, __float_as_int(x), CTRL, 0xF, 0xF, true));
}
template<int CTRL>
__device__ __forceinline__ int dppi(int x) {
    return __builtin_amdgcn_update_dpp(0, x, CTRL, 0xF, 0xF, true);
}

__device__ __forceinline__ void ce_desc(float& a, float& b) {
    float mx = fmaxf(a, b);
    float mn = fminf(a, b);
    a = mx; b = mn;
}

// One wave per (b, jb) tile of 11 instruments x 64 timesteps. Fully fused,
// read once / write once (NT stores keep the input L3-resident).
// - instrument tau (d=11): branch-free sort-network sparsemax. Support is a
//   prefix of the sorted order (Martins & Astudillo Lemma), so k_z and
//   cumsum[k_z-1] fall out of ONE masked pass. Exact, no iteration.
// - time tau (d=64, 4-lane groups x 16 elems): max-init Michelot, 3 fixed
//   branch-free iterations + exact count-stable tail loop. Nested-support
//   monotonicity (tau0 = max-1 <= tau*) makes count-stable == exact KKT.
__global__ __launch_bounds__(256) void fused_sparsemax_kernel(
        const float* __restrict__ in, float* __restrict__ out) {
    __shared__ float ldsz[4][NI * ROWP];   // z tile, row-major [inst][t]
    __shared__ float ldsti[4][64];         // tau_inst[t] transpose buffer

    const int lane = threadIdx.x & 63;
    const int wid  = threadIdx.x >> 6;
    const int tile = blockIdx.x * 4 + wid;          // 16384 tiles
    const int b    = tile >> 10;
    const int jb   = tile & (NBLK - 1);

    const float* px = in + (size_t)b * NI * T_ + (size_t)jb * LST + (size_t)lane;

    // ---- load: 11 coalesced 4B loads (one per instrument row) ----
    float z[NI];
#pragma unroll
    for (int i = 0; i < NI; ++i) z[i] = px[(size_t)i * T_];

    // stage tile to LDS immediately
#pragma unroll
    for (int i = 0; i < NI; ++i) ldsz[wid][i * ROWP + lane] = z[i];

    // read the transposed view early: LDS latency hides under the sort
    const int g   = lane >> 2;
    const int q   = lane & 3;
    const int row = (g < NI) ? g : (g - NI);        // spare groups duplicate

    float y[16];                                    // 4x ds_read_b128
#pragma unroll
    for (int r = 0; r < 16; ++r) y[r] = ldsz[wid][row * ROWP + q * 16 + r];

    // ---- instrument tau: exact, branch-free (sort + prefix pass) ----
    float s[NI];
#pragma unroll
    for (int i = 0; i < NI; ++i) s[i] = z[i];
#pragma unroll
    for (int p = 0; p < NI; ++p) {                  // OETS-11: 55 CE, 110 VALU
#pragma unroll
        for (int k = (p & 1); k + 1 < NI; k += 2) ce_desc(s[k], s[k + 1]);
    }
    float cum = 0.0f, tsum = 0.0f;
    int   kz  = 0;
#pragma unroll
    for (int k = 1; k <= NI; ++k) {
        cum += s[k - 1];
        bool cond = fmaf((float)k, s[k - 1], 1.0f) > cum;  // 1 + k*s_k > cum_k
        kz   += cond ? 1 : 0;                       // support size (prefix)
        tsum += cond ? s[k - 1] : 0.0f;             // == cumsum[k_z - 1]
    }
    const float tau_i = (tsum - 1.0f) * frcp((float)kz);
    ldsti[wid][lane] = tau_i;                       // lane == t within block

    // ---- time tau: max-init Michelot, 3 fixed iters + exact tail ----
    float m = y[0];
#pragma unroll
    for (int r = 1; r < 16; ++r) m = fmaxf(m, y[r]);
    m = fmaxf(m, dppf<DPP_XOR1>(m));
    m = fmaxf(m, dppf<DPP_XOR2>(m));

    float tau  = m - 1.0f;
    int   prev = 0;
#pragma unroll
    for (int it = 0; it < 3; ++it) {                // branch-free, ILP w/ sort
        float ss = 0.0f;
        int   cc = 0;
#pragma unroll
        for (int r = 0; r < 16; ++r) {
            bool a = y[r] > tau;
            ss += a ? y[r] : 0.0f;
            cc += a ? 1 : 0;
        }
        ss += dppf<DPP_XOR1>(ss);
        ss += dppf<DPP_XOR2>(ss);
        cc += dppi<DPP_XOR1>(cc);
        cc += dppi<DPP_XOR2>(cc);
        tau  = (ss - 1.0f) * frcp((float)cc);
        prev = cc;
    }
    for (int it = 0; it < LST; ++it) {              // exact tail, usually 1 pass
        float ss = 0.0f;
        int   cc = 0;
#pragma unroll
        for (int r = 0; r < 16; ++r) {
            bool a = y[r] > tau;
            ss += a ? y[r] : 0.0f;
            cc += a ? 1 : 0;
        }
        cc += dppi<DPP_XOR1>(cc);
        cc += dppi<DPP_XOR2>(cc);
        if (!__any(cc != prev)) break;              // stable set -> exact
        ss += dppf<DPP_XOR1>(ss);
        ss += dppf<DPP_XOR2>(ss);
        prev = cc;
        tau  = (ss - 1.0f) * frcp((float)cc);
    }

    // ---- epilogue in group layout: NT float4 stores ----
    if (g < NI) {
        float ti[16];                               // 4x ds_read_b128
#pragma unroll
        for (int r = 0; r < 16; ++r) ti[r] = ldsti[wid][q * 16 + r];

        float* po = out + (size_t)b * NI * T_ + (size_t)g * T_
                        + (size_t)jb * LST + (size_t)q * 16;
        f32x4* po4 = reinterpret_cast<f32x4*>(po);
#pragma unroll
        for (int v = 0; v < 4; ++v) {
            f32x4 o;
            o.x = fmaxf(y[4*v+0] - tau, 0.0f) * fmaxf(y[4*v+0] - ti[4*v+0], 0.0f);
            o.y = fmaxf(y[4*v+1] - tau, 0.0f) * fmaxf(y[4*v+1] - ti[4*v+1], 0.0f);
            o.z = fmaxf(y[4*v+2] - tau, 0.0f) * fmaxf(y[4*v+2] - ti[4*v+2], 0.0f);
            o.w = fmaxf(y[4*v+3] - tau, 0.0f) * fmaxf(y[4*v+3] - ti[4*v+3], 0.0f);
            __builtin_nontemporal_store(o, &po4[v]);   // output never re-read
        }
    }
}

extern "C" void kernel_launch(void* const* d_in, const int* in_sizes, int n_in,
                              void* d_out, int out_size, void* d_ws, size_t ws_size,
                              hipStream_t stream) {
    const float* in = (const float*)d_in[0];
    float* out = (float*)d_out;
    // 16384 wave-tiles, 4 waves per 256-thread block -> 4096 blocks
    hipLaunchKernelGGL(fused_sparsemax_kernel, dim3(4096), dim3(256), 0, stream,
                       in, out);
}

// Round 10
// 28.502 us; speedup vs baseline: 3.0015x; 2.2993x over previous
//
#include <hip/hip_runtime.h>

// Shapes fixed by reference setup_inputs(): (B=16, NI=11, T=65536), LST=64.
#define B_   16
#define NI   11
#define T_   65536
#define LST  64
#define NBLK (T_ / LST)     // 1024
#define ROWP 68             // LDS row stride (floats): 272B, 16B-aligned

#define DPP_XOR1 0xB1       // quad_perm(1,0,3,2)  == xor lane^1
#define DPP_XOR2 0x4E       // quad_perm(2,3,0,1)  == xor lane^2

__device__ __forceinline__ float frcp(float x) { return __builtin_amdgcn_rcpf(x); }

template<int CTRL>
__device__ __forceinline__ float dppf(float x) {
    return __int_as_float(__builtin_amdgcn_update_dpp(
        0, __float_as_int(x), CTRL, 0xF, 0xF, true));
}
template<int CTRL>
__device__ __forceinline__ int dppi(int x) {
    return __builtin_amdgcn_update_dpp(0, x, CTRL, 0xF, 0xF, true);
}

__device__ __forceinline__ void ce_desc(float& a, float& b) {
    float mx = fmaxf(a, b);
    float mn = fminf(a, b);
    a = mx; b = mn;
}

// One wave per (b, jb) tile of 11 instruments x 64 timesteps. Fully fused,
// read once / write once. REGULAR stores (R9 lesson: NT 16B stores bypass L2
// coalescing -> 2.6x HBM write amplification + latency stalls).
// - instrument tau (d=11): branch-free sort-network sparsemax. Support is a
//   prefix of the sorted order, so k_z and cumsum[k_z-1] come from ONE
//   masked pass. Exact, no iteration.
// - time tau (d=64, 4-lane groups x 16 elems): max-init Michelot, 3 fixed
//   branch-free iterations + exact count-stable tail loop. Nested-support
//   monotonicity (tau0 = max-1 <= tau*) makes count-stable == exact KKT.
__global__ __launch_bounds__(256) void fused_sparsemax_kernel(
        const float* __restrict__ in, float* __restrict__ out) {
    __shared__ float ldsz[4][NI * ROWP];   // z tile, row-major [inst][t]
    __shared__ float ldsti[4][64];         // tau_inst[t] transpose buffer

    const int lane = threadIdx.x & 63;
    const int wid  = threadIdx.x >> 6;
    const int tile = blockIdx.x * 4 + wid;          // 16384 tiles
    const int b    = tile >> 10;
    const int jb   = tile & (NBLK - 1);

    const float* px = in + (size_t)b * NI * T_ + (size_t)jb * LST + (size_t)lane;

    // ---- load: 11 coalesced 4B loads (one per instrument row) ----
    float z[NI];
#pragma unroll
    for (int i = 0; i < NI; ++i) z[i] = px[(size_t)i * T_];

    // stage tile to LDS immediately
#pragma unroll
    for (int i = 0; i < NI; ++i) ldsz[wid][i * ROWP + lane] = z[i];

    // read the transposed view early: LDS latency hides under the sort
    const int g   = lane >> 2;
    const int q   = lane & 3;
    const int row = (g < NI) ? g : (g - NI);        // spare groups duplicate

    float y[16];                                    // 4x ds_read_b128
#pragma unroll
    for (int r = 0; r < 16; ++r) y[r] = ldsz[wid][row * ROWP + q * 16 + r];

    // ---- instrument tau: exact, branch-free (sort + prefix pass) ----
    float s[NI];
#pragma unroll
    for (int i = 0; i < NI; ++i) s[i] = z[i];
#pragma unroll
    for (int p = 0; p < NI; ++p) {                  // OETS-11: 55 CE, 110 VALU
#pragma unroll
        for (int k = (p & 1); k + 1 < NI; k += 2) ce_desc(s[k], s[k + 1]);
    }
    float cum = 0.0f, tsum = 0.0f;
    int   kz  = 0;
#pragma unroll
    for (int k = 1; k <= NI; ++k) {
        cum += s[k - 1];
        bool cond = fmaf((float)k, s[k - 1], 1.0f) > cum;  // 1 + k*s_k > cum_k
        kz   += cond ? 1 : 0;                       // support size (prefix)
        tsum += cond ? s[k - 1] : 0.0f;             // == cumsum[k_z - 1]
    }
    const float tau_i = (tsum - 1.0f) * frcp((float)kz);
    ldsti[wid][lane] = tau_i;                       // lane == t within block

    // ---- time tau: max-init Michelot, 3 fixed iters + exact tail ----
    float m = y[0];
#pragma unroll
    for (int r = 1; r < 16; ++r) m = fmaxf(m, y[r]);
    m = fmaxf(m, dppf<DPP_XOR1>(m));
    m = fmaxf(m, dppf<DPP_XOR2>(m));

    float tau  = m - 1.0f;
    int   prev = 0;
#pragma unroll
    for (int it = 0; it < 3; ++it) {                // branch-free, ILP w/ sort
        float ss = 0.0f;
        int   cc = 0;
#pragma unroll
        for (int r = 0; r < 16; ++r) {
            bool a = y[r] > tau;
            ss += a ? y[r] : 0.0f;
            cc += a ? 1 : 0;
        }
        ss += dppf<DPP_XOR1>(ss);
        ss += dppf<DPP_XOR2>(ss);
        cc += dppi<DPP_XOR1>(cc);
        cc += dppi<DPP_XOR2>(cc);
        tau  = (ss - 1.0f) * frcp((float)cc);
        prev = cc;
    }
    for (int it = 0; it < LST; ++it) {              // exact tail, usually 1 pass
        float ss = 0.0f;
        int   cc = 0;
#pragma unroll
        for (int r = 0; r < 16; ++r) {
            bool a = y[r] > tau;
            ss += a ? y[r] : 0.0f;
            cc += a ? 1 : 0;
        }
        cc += dppi<DPP_XOR1>(cc);
        cc += dppi<DPP_XOR2>(cc);
        if (!__any(cc != prev)) break;              // stable set -> exact
        ss += dppf<DPP_XOR1>(ss);
        ss += dppf<DPP_XOR2>(ss);
        prev = cc;
        tau  = (ss - 1.0f) * frcp((float)cc);
    }

    // ---- epilogue in group layout: regular float4 stores (L2-coalesced) ----
    if (g < NI) {
        float ti[16];                               // 4x ds_read_b128
#pragma unroll
        for (int r = 0; r < 16; ++r) ti[r] = ldsti[wid][q * 16 + r];

        float* po = out + (size_t)b * NI * T_ + (size_t)g * T_
                        + (size_t)jb * LST + (size_t)q * 16;
        float4* po4 = reinterpret_cast<float4*>(po);
#pragma unroll
        for (int v = 0; v < 4; ++v) {
            float4 o;
            o.x = fmaxf(y[4*v+0] - tau, 0.0f) * fmaxf(y[4*v+0] - ti[4*v+0], 0.0f);
            o.y = fmaxf(y[4*v+1] - tau, 0.0f) * fmaxf(y[4*v+1] - ti[4*v+1], 0.0f);
            o.z = fmaxf(y[4*v+2] - tau, 0.0f) * fmaxf(y[4*v+2] - ti[4*v+2], 0.0f);
            o.w = fmaxf(y[4*v+3] - tau, 0.0f) * fmaxf(y[4*v+3] - ti[4*v+3], 0.0f);
            po4[v] = o;
        }
    }
}

extern "C" void kernel_launch(void* const* d_in, const int* in_sizes, int n_in,
                              void* d_out, int out_size, void* d_ws, size_t ws_size,
                              hipStream_t stream) {
    const float* in = (const float*)d_in[0];
    float* out = (float*)d_out;
    // 16384 wave-tiles, 4 waves per 256-thread block -> 4096 blocks
    hipLaunchKernelGGL(fused_sparsemax_kernel, dim3(4096), dim3(256), 0, stream,
                       in, out);
}